// Round 3
// baseline (251.008 us; speedup 1.0000x reference)
//
#include <hip/hip_runtime.h>
#include <hip/hip_bf16.h>

#define N_NODES 100000
#define NB 784   // buckets of 128 nodes: 784*128 = 100352 >= N_NODES
#define NPAD 100352
#define BSH 7
#define BMASK 127
#define CAP 4096   // static per-bucket capacity in ep/ssrc (mean 2040 -> safe)
#define LCAP 3584  // LDS copy of a bucket's sorted src list (max observed ~2300)
#define MSTRIDE 36 // u32 stride of an LDS mean row (32 payload + 4 pad)

typedef float v2f __attribute__((ext_vector_type(2)));

__device__ inline void fma4(float a, const float4& w, float4& c) {
  c.x = fmaf(a, w.x, c.x);
  c.y = fmaf(a, w.y, c.y);
  c.z = fmaf(a, w.z, c.z);
  c.w = fmaf(a, w.w, c.w);
}
__device__ inline unsigned short f2bf(float f) {  // RNE f32->bf16
  unsigned u = __float_as_uint(f);
  u += 0x7fffu + ((u >> 16) & 1u);
  return (unsigned short)(u >> 16);
}
__device__ inline unsigned pack2bf(float a, float b) {
  return (unsigned)f2bf(a) | ((unsigned)f2bf(b) << 16);
}
__device__ inline unsigned packfp8x4(float a, float b, float c, float d) {
  int pk = __builtin_amdgcn_cvt_pk_fp8_f32(a, b, 0, false);
  pk = __builtin_amdgcn_cvt_pk_fp8_f32(c, d, pk, true);
  return (unsigned)pk;
}
// relu(bf16(m) + bf16(s)) for 4 packed bf16 elements (bit-identical f32 math)
__device__ inline float4 relu_mix(uint2 m, uint2 s) {
  float4 v;
  v.x = fmaxf(__uint_as_float(m.x << 16) + __uint_as_float(s.x << 16), 0.f);
  v.y = fmaxf(__uint_as_float(m.x & 0xffff0000u) +
                  __uint_as_float(s.x & 0xffff0000u), 0.f);
  v.z = fmaxf(__uint_as_float(m.y << 16) + __uint_as_float(s.y << 16), 0.f);
  v.w = fmaxf(__uint_as_float(m.y & 0xffff0000u) +
                  __uint_as_float(s.y & 0xffff0000u), 0.f);
  return v;
}

#define EPB 2048  // edges per scatter-carrying block (8/thread)
#define EPT 8
#define GB1 1563  // ceil(100000/64)

// ---------------------------------------------------------------------------
// R16 fusedA: homogeneous blocks. Blocks [0,NSB) first run a 2048-edge
// scatter slice (2x the R15 scatter parallelism, half the per-block latency
// chain), then EVERY block runs a 64-row layer-1 dual-GEMM tile. lh/lbase
// alias the Ws LDS region (Ws is loaded after the scatter), keeping LDS at
// 32 KB -> 5 blocks/CU.
// ---------------------------------------------------------------------------
__global__ __launch_bounds__(256, 5) void fusedA_k(
    const int* __restrict__ src, const int* __restrict__ dst,
    unsigned* __restrict__ bcur, unsigned* __restrict__ ep,
    const float* __restrict__ x, const float* __restrict__ W1n,
    const float* __restrict__ W1s, const float* __restrict__ b1,
    unsigned* __restrict__ xnb8, unsigned short* __restrict__ xsb,
    int E, int NSB, int M) {
  __shared__ __align__(16) float smem[8192];  // 32768 B
  float* Wn = smem;
  float* Ws = smem + 4096;
  unsigned* lh = (unsigned*)Ws;      // [NB]  (aliases Ws; dead before Ws load)
  unsigned* lbase = lh + NB;         // [NB]
  const int tid = threadIdx.x;
  const int bid = blockIdx.x;

  // Wn load is independent of the scatter scratch region: issue it first.
  for (int i = tid; i < 1024; i += 256)
    ((float4*)Wn)[i] = ((const float4*)W1n)[i];

  if (bid < NSB) {
    // ---------------- scatter slice ----------------
    for (int i = tid; i < NB; i += 256) lh[i] = 0;
    __syncthreads();
    const int ebase = bid * EPB;
    int es[EPT], ed[EPT];
    unsigned short rk[EPT], bb[EPT];
#pragma unroll
    for (int it = 0; it < EPT; ++it) {
      int e = ebase + it * 256 + tid;
      if (e < E) {
        int d = dst[e];
        es[it] = src[e];
        ed[it] = d;
        unsigned bkt = ((unsigned)d) >> BSH;
        bb[it] = (unsigned short)bkt;
        rk[it] = (unsigned short)atomicAdd(&lh[bkt], 1u);
      }
    }
    __syncthreads();
    for (int i = tid; i < NB; i += 256)
      lbase[i] = lh[i] ? atomicAdd(&bcur[i], lh[i]) : 0u;
    __syncthreads();
#pragma unroll
    for (int it = 0; it < EPT; ++it) {
      int e = ebase + it * 256 + tid;
      if (e < E) {
        unsigned bkt = bb[it];
        ep[(size_t)bkt * CAP + lbase[bkt] + rk[it]] =
            (((unsigned)es[it]) << BSH) | (((unsigned)ed[it]) & BMASK);
      }
    }
    __syncthreads();  // all reads of lh/lbase done before Ws overwrites
  }

  // ---------------- gemm1 (all blocks) ----------------
  for (int i = tid; i < 1024; i += 256)
    ((float4*)Ws)[i] = ((const float4*)W1s)[i];

  const int row0 = bid * 64;
  const int tx = tid & 15;
  const int ty = tid >> 4;
  const int arow = ty * 4;

  const float* xr[4];
#pragma unroll
  for (int r = 0; r < 4; ++r) {
    long long gr = row0 + arow + r;
    if (gr >= M) gr = M - 1;
    xr[r] = x + gr * 64;
  }

  float4 an[4], as[4];
#pragma unroll
  for (int r = 0; r < 4; ++r) {
    an[r] = make_float4(0.f, 0.f, 0.f, 0.f);
    as[r] = make_float4(0.f, 0.f, 0.f, 0.f);
  }
  __syncthreads();

#pragma unroll 2
  for (int k4 = 0; k4 < 16; ++k4) {
    float4 a[4];
#pragma unroll
    for (int r = 0; r < 4; ++r) a[r] = *(const float4*)(xr[r] + 4 * k4);
    float4 wn0 = *(const float4*)&Wn[(4 * k4 + 0) * 64 + 4 * tx];
    float4 wn1 = *(const float4*)&Wn[(4 * k4 + 1) * 64 + 4 * tx];
    float4 wn2 = *(const float4*)&Wn[(4 * k4 + 2) * 64 + 4 * tx];
    float4 wn3 = *(const float4*)&Wn[(4 * k4 + 3) * 64 + 4 * tx];
    float4 ws0 = *(const float4*)&Ws[(4 * k4 + 0) * 64 + 4 * tx];
    float4 ws1 = *(const float4*)&Ws[(4 * k4 + 1) * 64 + 4 * tx];
    float4 ws2 = *(const float4*)&Ws[(4 * k4 + 2) * 64 + 4 * tx];
    float4 ws3 = *(const float4*)&Ws[(4 * k4 + 3) * 64 + 4 * tx];
#pragma unroll
    for (int r = 0; r < 4; ++r) {
      fma4(a[r].x, wn0, an[r]);
      fma4(a[r].y, wn1, an[r]);
      fma4(a[r].z, wn2, an[r]);
      fma4(a[r].w, wn3, an[r]);
      fma4(a[r].x, ws0, as[r]);
      fma4(a[r].y, ws1, as[r]);
      fma4(a[r].z, ws2, as[r]);
      fma4(a[r].w, ws3, as[r]);
    }
  }

  const float4 bv = *(const float4*)&b1[4 * tx];
#pragma unroll
  for (int r = 0; r < 4; ++r) {
    int row = row0 + arow + r;
    if (row < M) {
      ushort4 ps;
      ps.x = f2bf(as[r].x + bv.x);
      ps.y = f2bf(as[r].y + bv.y);
      ps.z = f2bf(as[r].z + bv.z);
      ps.w = f2bf(as[r].w + bv.w);
      *(ushort4*)&xsb[(long long)row * 64 + 4 * tx] = ps;
      xnb8[(size_t)row * 16 + tx] =
          packfp8x4(an[r].x, an[r].y, an[r].z, an[r].w);
    }
  }
}

// ---------------------------------------------------------------------------
// R16 fggs: one block per bucket (128 nodes). Phase S: counting sort of the
// bucket's edges (identical algorithm to the old bsort_k; sorted src list
// kept in LDS, written through to global ssrc for gather2; rows2 written for
// gather2). Phase G: two 64-node passes of {fp8 gather-mean -> bf16 in LDS,
// 64-row dual GEMM2}. Removes the serial bsort dispatch entirely.
// LDS = 8K(Wn)+8K(Ws)+14K(ssrc_l)+9K(mlds)+1K(cnt/sc) = 40960 B -> 4 blk/CU.
// ---------------------------------------------------------------------------
__global__ __launch_bounds__(256, 4) void fggs_k(
    const uint4* __restrict__ valb4, const unsigned* __restrict__ ep,
    const unsigned* __restrict__ bcur, int* __restrict__ ssrc,
    uint2* __restrict__ rows2, const unsigned short* __restrict__ xsb,
    const float* __restrict__ W2n, const float* __restrict__ W2s,
    const float* __restrict__ b2, unsigned* __restrict__ hnb8,
    float* __restrict__ hs, int M) {
  __shared__ float Wn[64 * 32];
  __shared__ float Ws[64 * 32];
  __shared__ unsigned ssrc_l[LCAP];
  __shared__ unsigned mlds[64 * MSTRIDE];
  __shared__ unsigned cnt[128];
  __shared__ unsigned sc[128];
  const int tid = threadIdx.x;
  const int b = blockIdx.x;
  const unsigned cntb = bcur[b];
  const unsigned beg = (unsigned)(b * CAP);

  for (int i = tid; i < 512; i += 256) {
    ((float4*)Wn)[i] = ((const float4*)W2n)[i];
    ((float4*)Ws)[i] = ((const float4*)W2s)[i];
  }
  if (tid < 128) cnt[tid] = 0;
  __syncthreads();

  // ---- Phase S: counting sort by node-in-bucket ----
  for (unsigned j = tid; j < cntb; j += 256)
    atomicAdd(&cnt[ep[(size_t)beg + j] & BMASK], 1u);
  __syncthreads();
  unsigned v = (tid < 128) ? cnt[tid] : 0u;
  if (tid < 128) sc[tid] = v;
  __syncthreads();
  for (int off = 1; off < 128; off <<= 1) {
    unsigned t = (tid < 128 && tid >= off) ? sc[tid - off] : 0u;
    __syncthreads();
    if (tid < 128) sc[tid] += t;
    __syncthreads();
  }
  if (tid < 128) {
    unsigned ex = sc[tid] - v;
    rows2[b * 128 + tid] = make_uint2(beg + ex, beg + ex + v);
    cnt[tid] = ex | (v << 16);  // low: cursor (starts at ex), high: count
  }
  __syncthreads();
  // grab this thread's two node-run descriptors before cursors mutate
  const int ln = tid >> 2;
  const int p4 = tid & 3;
  const unsigned cpk0 = cnt[ln];
  const unsigned cpk1 = cnt[64 + ln];
  __syncthreads();
  for (unsigned j = tid; j < cntb; j += 256) {
    unsigned pv = ep[(size_t)beg + j];
    unsigned r = atomicAdd(&cnt[pv & BMASK], 1u) & 0xffffu;  // ex+k < 4096
    unsigned s = pv >> BSH;
    ssrc[(size_t)beg + r] = (int)s;   // write-through for gather2
    if (r < LCAP) ssrc_l[r] = s;
  }
  __syncthreads();

  // generic pointer: LDS copy when it fits (always, for this data),
  // else the global (just-written) list.
  const unsigned* sl = (cntb <= (unsigned)LCAP)
                           ? (const unsigned*)ssrc_l
                           : (const unsigned*)ssrc + beg;

  // ---- Phase G: two passes of {gather 64 nodes, gemm 64 rows} ----
#pragma unroll
  for (int pp = 0; pp < 2; ++pp) {
    const unsigned cpk = pp ? cpk1 : cpk0;
    const unsigned lbeg = cpk & 0xffffu;
    const unsigned dg = cpk >> 16;
    const unsigned lend = lbeg + dg;

    float acc[16];
#pragma unroll
    for (int q = 0; q < 16; ++q) acc[q] = 0.f;

    unsigned j = lbeg;
    for (; j + 8 <= lend; j += 8) {
      unsigned sn[8];
#pragma unroll
      for (int i = 0; i < 8; ++i) sn[i] = sl[j + i];
      uint4 u[8];
#pragma unroll
      for (int i = 0; i < 8; ++i) u[i] = valb4[(size_t)sn[i] * 4 + p4];
#pragma unroll
      for (int i = 0; i < 8; ++i) {
        v2f f0 = __builtin_amdgcn_cvt_pk_f32_fp8((int)u[i].x, false);
        v2f f1 = __builtin_amdgcn_cvt_pk_f32_fp8((int)u[i].x, true);
        v2f f2 = __builtin_amdgcn_cvt_pk_f32_fp8((int)u[i].y, false);
        v2f f3 = __builtin_amdgcn_cvt_pk_f32_fp8((int)u[i].y, true);
        v2f f4 = __builtin_amdgcn_cvt_pk_f32_fp8((int)u[i].z, false);
        v2f f5 = __builtin_amdgcn_cvt_pk_f32_fp8((int)u[i].z, true);
        v2f f6 = __builtin_amdgcn_cvt_pk_f32_fp8((int)u[i].w, false);
        v2f f7 = __builtin_amdgcn_cvt_pk_f32_fp8((int)u[i].w, true);
        acc[0] += f0[0];  acc[1] += f0[1];
        acc[2] += f1[0];  acc[3] += f1[1];
        acc[4] += f2[0];  acc[5] += f2[1];
        acc[6] += f3[0];  acc[7] += f3[1];
        acc[8] += f4[0];  acc[9] += f4[1];
        acc[10] += f5[0]; acc[11] += f5[1];
        acc[12] += f6[0]; acc[13] += f6[1];
        acc[14] += f7[0]; acc[15] += f7[1];
      }
    }
    if (j < lend) {
      const unsigned last = lend - 1;
      unsigned sn[8];
#pragma unroll
      for (int i = 0; i < 8; ++i) {
        unsigned jj = j + i;
        sn[i] = sl[jj < last ? jj : last];
      }
      uint4 u[8];
#pragma unroll
      for (int i = 0; i < 8; ++i) u[i] = valb4[(size_t)sn[i] * 4 + p4];
#pragma unroll
      for (int i = 0; i < 8; ++i) {
        float w = ((j + i) < lend) ? 1.f : 0.f;
        v2f f0 = __builtin_amdgcn_cvt_pk_f32_fp8((int)u[i].x, false);
        v2f f1 = __builtin_amdgcn_cvt_pk_f32_fp8((int)u[i].x, true);
        v2f f2 = __builtin_amdgcn_cvt_pk_f32_fp8((int)u[i].y, false);
        v2f f3 = __builtin_amdgcn_cvt_pk_f32_fp8((int)u[i].y, true);
        v2f f4 = __builtin_amdgcn_cvt_pk_f32_fp8((int)u[i].z, false);
        v2f f5 = __builtin_amdgcn_cvt_pk_f32_fp8((int)u[i].z, true);
        v2f f6 = __builtin_amdgcn_cvt_pk_f32_fp8((int)u[i].w, false);
        v2f f7 = __builtin_amdgcn_cvt_pk_f32_fp8((int)u[i].w, true);
        acc[0] = fmaf(w, f0[0], acc[0]);   acc[1] = fmaf(w, f0[1], acc[1]);
        acc[2] = fmaf(w, f1[0], acc[2]);   acc[3] = fmaf(w, f1[1], acc[3]);
        acc[4] = fmaf(w, f2[0], acc[4]);   acc[5] = fmaf(w, f2[1], acc[5]);
        acc[6] = fmaf(w, f3[0], acc[6]);   acc[7] = fmaf(w, f3[1], acc[7]);
        acc[8] = fmaf(w, f4[0], acc[8]);   acc[9] = fmaf(w, f4[1], acc[9]);
        acc[10] = fmaf(w, f5[0], acc[10]); acc[11] = fmaf(w, f5[1], acc[11]);
        acc[12] = fmaf(w, f6[0], acc[12]); acc[13] = fmaf(w, f6[1], acc[13]);
        acc[14] = fmaf(w, f7[0], acc[14]); acc[15] = fmaf(w, f7[1], acc[15]);
      }
    }

    const float inv = dg ? 1.f / (float)dg : 0.f;
    uint4 pk0, pk1;
    pk0.x = pack2bf(acc[0] * inv, acc[1] * inv);
    pk0.y = pack2bf(acc[2] * inv, acc[3] * inv);
    pk0.z = pack2bf(acc[4] * inv, acc[5] * inv);
    pk0.w = pack2bf(acc[6] * inv, acc[7] * inv);
    pk1.x = pack2bf(acc[8] * inv, acc[9] * inv);
    pk1.y = pack2bf(acc[10] * inv, acc[11] * inv);
    pk1.z = pack2bf(acc[12] * inv, acc[13] * inv);
    pk1.w = pack2bf(acc[14] * inv, acc[15] * inv);
    *(uint4*)&mlds[ln * MSTRIDE + p4 * 8] = pk0;
    *(uint4*)&mlds[ln * MSTRIDE + p4 * 8 + 4] = pk1;
    __syncthreads();

    // ---- 64-row dual GEMM2 ----
    const int tx = tid & 7;
    const int ty = tid >> 3;  // 0..31
    const int arow = ty * 2;
    const int node0p = b * 128 + pp * 64;

    const uint2* mp[2];
    const uint2* sp[2];
#pragma unroll
    for (int r = 0; r < 2; ++r) {
      long long gr = node0p + arow + r;
      if (gr >= M) gr = M - 1;
      mp[r] = (const uint2*)&mlds[(arow + r) * MSTRIDE];
      sp[r] = (const uint2*)(xsb + gr * 64);
    }

    float4 an[2], as[2];
#pragma unroll
    for (int r = 0; r < 2; ++r) {
      an[r] = make_float4(0.f, 0.f, 0.f, 0.f);
      as[r] = make_float4(0.f, 0.f, 0.f, 0.f);
    }

#pragma unroll 2
    for (int k4 = 0; k4 < 16; ++k4) {
      float4 a[2];
#pragma unroll
      for (int r = 0; r < 2; ++r) a[r] = relu_mix(mp[r][k4], sp[r][k4]);
      float4 wn0 = *(const float4*)&Wn[(4 * k4 + 0) * 32 + 4 * tx];
      float4 wn1 = *(const float4*)&Wn[(4 * k4 + 1) * 32 + 4 * tx];
      float4 wn2 = *(const float4*)&Wn[(4 * k4 + 2) * 32 + 4 * tx];
      float4 wn3 = *(const float4*)&Wn[(4 * k4 + 3) * 32 + 4 * tx];
      float4 ws0 = *(const float4*)&Ws[(4 * k4 + 0) * 32 + 4 * tx];
      float4 ws1 = *(const float4*)&Ws[(4 * k4 + 1) * 32 + 4 * tx];
      float4 ws2 = *(const float4*)&Ws[(4 * k4 + 2) * 32 + 4 * tx];
      float4 ws3 = *(const float4*)&Ws[(4 * k4 + 3) * 32 + 4 * tx];
#pragma unroll
      for (int r = 0; r < 2; ++r) {
        fma4(a[r].x, wn0, an[r]);
        fma4(a[r].y, wn1, an[r]);
        fma4(a[r].z, wn2, an[r]);
        fma4(a[r].w, wn3, an[r]);
        fma4(a[r].x, ws0, as[r]);
        fma4(a[r].y, ws1, as[r]);
        fma4(a[r].z, ws2, as[r]);
        fma4(a[r].w, ws3, as[r]);
      }
    }

    const float4 bvv = *(const float4*)&b2[4 * tx];
#pragma unroll
    for (int r = 0; r < 2; ++r) {
      int row = node0p + arow + r;
      if (row < M) {
        float4 o;
        o.x = as[r].x + bvv.x;
        o.y = as[r].y + bvv.y;
        o.z = as[r].z + bvv.z;
        o.w = as[r].w + bvv.w;
        *(float4*)&hs[(long long)row * 32 + 4 * tx] = o;
        hnb8[(size_t)row * 8 + tx] =
            packfp8x4(an[r].x, an[r].y, an[r].z, an[r].w);
      }
    }
    __syncthreads();  // mlds reused by pass 1
  }
}

// ---------------------------------------------------------------------------
// gather2: out[node][:] = mean_j fp8decode(hnb8[ssrc[j]][:]) + hs[node][:]
// Row = 32 fp8 = 32 B; table 3.2 MB -> L2-resident. P=2 lanes/node.
// ---------------------------------------------------------------------------
__global__ __launch_bounds__(256) void gather2_k(
    const uint4* __restrict__ valb4, const int* __restrict__ ssrc,
    const uint2* __restrict__ rows2, const float* __restrict__ base,
    float* __restrict__ out, int N) {
  constexpr int P = 2;
  const int node = blockIdx.x * 128 + threadIdx.x / P;
  const int p = threadIdx.x & 1;
  if (node >= N) return;
  const uint2 be = rows2[node];
  const unsigned beg = be.x, end = be.y;

  float acc[16];
#pragma unroll
  for (int q = 0; q < 16; ++q) acc[q] = 0.f;

  unsigned j = beg;
  for (; j + 8 <= end; j += 8) {
    int sn[8];
#pragma unroll
    for (int i = 0; i < 8; ++i) sn[i] = ssrc[j + i];
    uint4 u[8];
#pragma unroll
    for (int i = 0; i < 8; ++i) u[i] = valb4[(size_t)sn[i] * P + p];
#pragma unroll
    for (int i = 0; i < 8; ++i) {
      v2f f0 = __builtin_amdgcn_cvt_pk_f32_fp8((int)u[i].x, false);
      v2f f1 = __builtin_amdgcn_cvt_pk_f32_fp8((int)u[i].x, true);
      v2f f2 = __builtin_amdgcn_cvt_pk_f32_fp8((int)u[i].y, false);
      v2f f3 = __builtin_amdgcn_cvt_pk_f32_fp8((int)u[i].y, true);
      v2f f4 = __builtin_amdgcn_cvt_pk_f32_fp8((int)u[i].z, false);
      v2f f5 = __builtin_amdgcn_cvt_pk_f32_fp8((int)u[i].z, true);
      v2f f6 = __builtin_amdgcn_cvt_pk_f32_fp8((int)u[i].w, false);
      v2f f7 = __builtin_amdgcn_cvt_pk_f32_fp8((int)u[i].w, true);
      acc[0] += f0[0];  acc[1] += f0[1];
      acc[2] += f1[0];  acc[3] += f1[1];
      acc[4] += f2[0];  acc[5] += f2[1];
      acc[6] += f3[0];  acc[7] += f3[1];
      acc[8] += f4[0];  acc[9] += f4[1];
      acc[10] += f5[0]; acc[11] += f5[1];
      acc[12] += f6[0]; acc[13] += f6[1];
      acc[14] += f7[0]; acc[15] += f7[1];
    }
  }
  if (j < end) {
    const unsigned last = end - 1;
    int sn[8];
#pragma unroll
    for (int i = 0; i < 8; ++i) {
      unsigned jj = j + i;
      sn[i] = ssrc[jj < last ? jj : last];
    }
    uint4 u[8];
#pragma unroll
    for (int i = 0; i < 8; ++i) u[i] = valb4[(size_t)sn[i] * P + p];
#pragma unroll
    for (int i = 0; i < 8; ++i) {
      float w = ((j + i) < end) ? 1.f : 0.f;
      v2f f0 = __builtin_amdgcn_cvt_pk_f32_fp8((int)u[i].x, false);
      v2f f1 = __builtin_amdgcn_cvt_pk_f32_fp8((int)u[i].x, true);
      v2f f2 = __builtin_amdgcn_cvt_pk_f32_fp8((int)u[i].y, false);
      v2f f3 = __builtin_amdgcn_cvt_pk_f32_fp8((int)u[i].y, true);
      v2f f4 = __builtin_amdgcn_cvt_pk_f32_fp8((int)u[i].z, false);
      v2f f5 = __builtin_amdgcn_cvt_pk_f32_fp8((int)u[i].z, true);
      v2f f6 = __builtin_amdgcn_cvt_pk_f32_fp8((int)u[i].w, false);
      v2f f7 = __builtin_amdgcn_cvt_pk_f32_fp8((int)u[i].w, true);
      acc[0] = fmaf(w, f0[0], acc[0]);   acc[1] = fmaf(w, f0[1], acc[1]);
      acc[2] = fmaf(w, f1[0], acc[2]);   acc[3] = fmaf(w, f1[1], acc[3]);
      acc[4] = fmaf(w, f2[0], acc[4]);   acc[5] = fmaf(w, f2[1], acc[5]);
      acc[6] = fmaf(w, f3[0], acc[6]);   acc[7] = fmaf(w, f3[1], acc[7]);
      acc[8] = fmaf(w, f4[0], acc[8]);   acc[9] = fmaf(w, f4[1], acc[9]);
      acc[10] = fmaf(w, f5[0], acc[10]); acc[11] = fmaf(w, f5[1], acc[11]);
      acc[12] = fmaf(w, f6[0], acc[12]); acc[13] = fmaf(w, f6[1], acc[13]);
      acc[14] = fmaf(w, f7[0], acc[14]); acc[15] = fmaf(w, f7[1], acc[15]);
    }
  }

  const unsigned dg = end - beg;
  const float inv = dg ? 1.f / (float)dg : 0.f;
  const size_t o = (size_t)node * 32 + 16 * p;
#pragma unroll
  for (int q4 = 0; q4 < 4; ++q4) {
    float4 bv = *(const float4*)&base[o + 4 * q4];
    float4 ov;
    ov.x = acc[4 * q4 + 0] * inv + bv.x;
    ov.y = acc[4 * q4 + 1] * inv + bv.y;
    ov.z = acc[4 * q4 + 2] * inv + bv.z;
    ov.w = acc[4 * q4 + 3] * inv + bv.w;
    *(float4*)&out[o + 4 * q4] = ov;
  }
}

extern "C" void kernel_launch(void* const* d_in, const int* in_sizes, int n_in,
                              void* d_out, int out_size, void* d_ws,
                              size_t ws_size, hipStream_t stream) {
  const float* x   = (const float*)d_in[0];
  const int*   ei  = (const int*)d_in[1];  // [2, E]: row0 = src, row1 = dst
  const float* W1n = (const float*)d_in[2];
  const float* W1s = (const float*)d_in[3];
  const float* b1  = (const float*)d_in[4];
  const float* W2n = (const float*)d_in[5];
  const float* W2s = (const float*)d_in[6];
  const float* b2  = (const float*)d_in[7];
  float* out = (float*)d_out;

  const int E = in_sizes[1] / 2;  // 1,600,000
  const int M = N_NODES;
  const int* src = ei;
  const int* dst = ei + E;
  const int NSB = (E + EPB - 1) / EPB;  // 782

  // Workspace layout (bytes):
  //   ep    @ 0           12,845,056  (NB*CAP u32; fggs reads -> NOT aliased)
  //   ssrc  @ 12,845,056  12,845,056
  //   rows2 @ 25,690,112     802,816
  //   bcur  @ 26,492,928       3,136
  //   xnb8  @ 26,496,064   6,400,000  (fp8 M x 64)
  //   xsb   @ 32,896,064  12,800,000  (bf16 M x 64)
  //   hnb8  @ 45,696,064   3,211,264  (fp8 M x 32)
  //   hs    @ 58,496,064  12,800,000  (f32 M x 32)
  char* wsb = (char*)d_ws;
  unsigned*       ep    = (unsigned*)(wsb);
  int*            ssrc  = (int*)(wsb + 12845056);
  uint2*          rows2 = (uint2*)(wsb + 25690112);
  unsigned*       bcur  = (unsigned*)(wsb + 26492928);
  unsigned*       xnb8  = (unsigned*)(wsb + 26496064);
  unsigned short* xsb   = (unsigned short*)(wsb + 32896064);
  unsigned*       hnb8  = (unsigned*)(wsb + 45696064);
  float*          hs    = (float*)(wsb + 58496064);

  // 1) zero bucket cursors (3 KB)
  hipMemsetAsync(bcur, 0, NB * 4, stream);
  // 2) homogeneous fusedA: scatter slices (blocks < NSB) + layer-1 dual-GEMM
  fusedA_k<<<GB1, 256, 0, stream>>>(src, dst, bcur, ep, x, W1n, W1s, b1,
                                    xnb8, xsb, E, NSB, M);
  // 3) fused per-bucket sort + gather1-mean + gemm2 (one block per bucket)
  fggs_k<<<NB, 256, 0, stream>>>((const uint4*)xnb8, ep, bcur, ssrc, rows2,
                                 xsb, W2n, W2s, b2, hnb8, hs, M);
  // 4) out = mean(fp8(hn)[src]) + hs
  gather2_k<<<(M + 127) / 128, 256, 0, stream>>>((const uint4*)hnb8, ssrc,
                                                 rows2, hs, out, M);
}

// Round 4
// 195.866 us; speedup vs baseline: 1.2815x; 1.2815x over previous
//
#include <hip/hip_runtime.h>
#include <hip/hip_bf16.h>

#define N_NODES 100000
#define NB 784   // buckets of 128 nodes: 784*128 = 100352 >= N_NODES
#define NPAD 100352
#define BSH 7
#define BMASK 127
#define CAP 4096  // static per-bucket capacity (mean 2040 -> safe)
#define MSTRIDE 36 // u32 stride of an LDS mean row (32 payload + 4 pad)

typedef float v2f __attribute__((ext_vector_type(2)));

__device__ inline void fma4(float a, const float4& w, float4& c) {
  c.x = fmaf(a, w.x, c.x);
  c.y = fmaf(a, w.y, c.y);
  c.z = fmaf(a, w.z, c.z);
  c.w = fmaf(a, w.w, c.w);
}
__device__ inline unsigned short f2bf(float f) {  // RNE f32->bf16
  unsigned u = __float_as_uint(f);
  u += 0x7fffu + ((u >> 16) & 1u);
  return (unsigned short)(u >> 16);
}
__device__ inline unsigned pack2bf(float a, float b) {
  return (unsigned)f2bf(a) | ((unsigned)f2bf(b) << 16);
}
__device__ inline unsigned packfp8x4(float a, float b, float c, float d) {
  int pk = __builtin_amdgcn_cvt_pk_fp8_f32(a, b, 0, false);
  pk = __builtin_amdgcn_cvt_pk_fp8_f32(c, d, pk, true);
  return (unsigned)pk;
}
// relu(bf16(m) + bf16(s)) for 4 packed bf16 elements (bit-identical f32 math)
__device__ inline float4 relu_mix(uint2 m, uint2 s) {
  float4 v;
  v.x = fmaxf(__uint_as_float(m.x << 16) + __uint_as_float(s.x << 16), 0.f);
  v.y = fmaxf(__uint_as_float(m.x & 0xffff0000u) +
                  __uint_as_float(s.x & 0xffff0000u), 0.f);
  v.z = fmaxf(__uint_as_float(m.y << 16) + __uint_as_float(s.y << 16), 0.f);
  v.w = fmaxf(__uint_as_float(m.y & 0xffff0000u) +
                  __uint_as_float(s.y & 0xffff0000u), 0.f);
  return v;
}

#define EPB 8192   // edges per scatter block (R17: halves partial-line writes)
#define EPT 32     // edges per thread (256 threads)
#define GB1 1563   // ceil(100000/64)

// ---------------------------------------------------------------------------
// R17 fusedA: blocks [0,NSB) = scatter-only (256 thr x 32 edges; 196 blocks
// -> per-(block,bucket) runs of ~10.4 edges = 42 B, cutting partial-line RMW
// vs R15's 391 blocks). Edge src/dst re-read in the store phase (L2/L3-hot)
// so only a packed (rank<<10|bucket) u32 per edge stays in registers.
// Blocks [NSB, NSB+GB1) = layer-1 dual-GEMM (identical to R15).
// ---------------------------------------------------------------------------
__global__ __launch_bounds__(256) void fusedA_k(
    const int* __restrict__ src, const int* __restrict__ dst,
    unsigned* __restrict__ bcur, unsigned* __restrict__ ep,
    const float* __restrict__ x, const float* __restrict__ W1n,
    const float* __restrict__ W1s, const float* __restrict__ b1,
    unsigned* __restrict__ xnb8, unsigned short* __restrict__ xsb,
    int E, int NSB, int M) {
  __shared__ __align__(16) float smem[8192];  // 32768 B
  const int tid = threadIdx.x;

  if ((int)blockIdx.x < NSB) {
    // ---------------- scatter body ----------------
    unsigned* lh = (unsigned*)smem;
    unsigned* lbase = lh + NB;
    for (int i = tid; i < NB; i += 256) lh[i] = 0;
    __syncthreads();
    const int ebase = blockIdx.x * EPB;
    unsigned rb[EPT];  // (rank<<10) | bucket
#pragma unroll
    for (int it = 0; it < EPT; ++it) {
      int e = ebase + it * 256 + tid;
      if (e < E) {
        unsigned b = ((unsigned)dst[e]) >> BSH;
        unsigned r = atomicAdd(&lh[b], 1u);  // r < 8192 -> fits in 22 bits
        rb[it] = (r << 10) | b;
      }
    }
    __syncthreads();
    for (int i = tid; i < NB; i += 256)
      lbase[i] = lh[i] ? atomicAdd(&bcur[i], lh[i]) : 0u;
    __syncthreads();
#pragma unroll
    for (int it = 0; it < EPT; ++it) {
      int e = ebase + it * 256 + tid;
      if (e < E) {
        unsigned b = rb[it] & 1023u;
        unsigned r = rb[it] >> 10;
        ep[(size_t)b * CAP + lbase[b] + r] =
            (((unsigned)src[e]) << BSH) | (((unsigned)dst[e]) & BMASK);
      }
    }
    return;
  }

  // ---------------- gemm1 body ----------------
  float* Wn = smem;
  float* Ws = smem + 4096;
  const int row0 = ((int)blockIdx.x - NSB) * 64;

  for (int i = tid; i < 1024; i += 256) {
    ((float4*)Wn)[i] = ((const float4*)W1n)[i];
    ((float4*)Ws)[i] = ((const float4*)W1s)[i];
  }

  const int tx = tid & 15;
  const int ty = tid >> 4;
  const int arow = ty * 4;

  // clamped per-row global pointers (A reads are 16-lane broadcasts via L1)
  const float* xr[4];
#pragma unroll
  for (int r = 0; r < 4; ++r) {
    long long gr = row0 + arow + r;
    if (gr >= M) gr = M - 1;
    xr[r] = x + gr * 64;
  }

  float4 an[4], as[4];
#pragma unroll
  for (int r = 0; r < 4; ++r) {
    an[r] = make_float4(0.f, 0.f, 0.f, 0.f);
    as[r] = make_float4(0.f, 0.f, 0.f, 0.f);
  }
  __syncthreads();

#pragma unroll 2
  for (int k4 = 0; k4 < 16; ++k4) {
    float4 a[4];
#pragma unroll
    for (int r = 0; r < 4; ++r) a[r] = *(const float4*)(xr[r] + 4 * k4);
    float4 wn0 = *(const float4*)&Wn[(4 * k4 + 0) * 64 + 4 * tx];
    float4 wn1 = *(const float4*)&Wn[(4 * k4 + 1) * 64 + 4 * tx];
    float4 wn2 = *(const float4*)&Wn[(4 * k4 + 2) * 64 + 4 * tx];
    float4 wn3 = *(const float4*)&Wn[(4 * k4 + 3) * 64 + 4 * tx];
    float4 ws0 = *(const float4*)&Ws[(4 * k4 + 0) * 64 + 4 * tx];
    float4 ws1 = *(const float4*)&Ws[(4 * k4 + 1) * 64 + 4 * tx];
    float4 ws2 = *(const float4*)&Ws[(4 * k4 + 2) * 64 + 4 * tx];
    float4 ws3 = *(const float4*)&Ws[(4 * k4 + 3) * 64 + 4 * tx];
#pragma unroll
    for (int r = 0; r < 4; ++r) {
      fma4(a[r].x, wn0, an[r]);
      fma4(a[r].y, wn1, an[r]);
      fma4(a[r].z, wn2, an[r]);
      fma4(a[r].w, wn3, an[r]);
      fma4(a[r].x, ws0, as[r]);
      fma4(a[r].y, ws1, as[r]);
      fma4(a[r].z, ws2, as[r]);
      fma4(a[r].w, ws3, as[r]);
    }
  }

  const float4 bv = *(const float4*)&b1[4 * tx];
#pragma unroll
  for (int r = 0; r < 4; ++r) {
    int row = row0 + arow + r;
    if (row < M) {
      ushort4 ps;
      ps.x = f2bf(as[r].x + bv.x);
      ps.y = f2bf(as[r].y + bv.y);
      ps.z = f2bf(as[r].z + bv.z);
      ps.w = f2bf(as[r].w + bv.w);
      *(ushort4*)&xsb[(long long)row * 64 + 4 * tx] = ps;
      xnb8[(size_t)row * 16 + tx] =
          packfp8x4(an[r].x, an[r].y, an[r].z, an[r].w);
    }
  }
}

// ---------------------------------------------------------------------------
// bsort: per-bucket counting sort by dst&127 -> per-node contiguous src runs.
// ---------------------------------------------------------------------------
__global__ __launch_bounds__(256) void bsort_k(const unsigned* __restrict__ ep,
                                               const unsigned* __restrict__ bcur,
                                               int* __restrict__ ssrc,
                                               uint2* __restrict__ rows2) {
  __shared__ unsigned cnt[128];
  __shared__ unsigned sc[128];
  const int tid = threadIdx.x;
  const int b = blockIdx.x;
  const unsigned cntb = bcur[b];
  const unsigned beg = (unsigned)(b * CAP);
  if (tid < 128) cnt[tid] = 0;
  __syncthreads();
  for (unsigned j = tid; j < cntb; j += 256)
    atomicAdd(&cnt[ep[(size_t)beg + j] & BMASK], 1u);
  __syncthreads();
  unsigned v = (tid < 128) ? cnt[tid] : 0u;
  if (tid < 128) sc[tid] = v;
  __syncthreads();
  for (int off = 1; off < 128; off <<= 1) {
    unsigned t = (tid < 128 && tid >= off) ? sc[tid - off] : 0u;
    __syncthreads();
    if (tid < 128) sc[tid] += t;
    __syncthreads();
  }
  if (tid < 128) {
    unsigned ex = sc[tid] - v;
    rows2[b * 128 + tid] = make_uint2(beg + ex, beg + ex + v);
    cnt[tid] = ex;
  }
  __syncthreads();
  for (unsigned j = tid; j < cntb; j += 256) {
    unsigned p = ep[(size_t)beg + j];
    unsigned r = atomicAdd(&cnt[p & BMASK], 1u);
    ssrc[(size_t)beg + r] = (int)(p >> BSH);
  }
}

// ---------------------------------------------------------------------------
// fgg: fused gather1 + gemm2 per 64 nodes (R15-proven). Gather phase computes
// mean_j fp8decode(xnb8[ssrc[j]]) -> bf16-packed rows in LDS (stride 36 u32);
// GEMM phase does hn(fp8)/hs = relu(mean+xs)@{W2n,W2s}+b2.
// ---------------------------------------------------------------------------
__global__ __launch_bounds__(256) void fgg_k(
    const uint4* __restrict__ valb4, const int* __restrict__ ssrc,
    const uint2* __restrict__ rows2, const unsigned short* __restrict__ xsb,
    const float* __restrict__ W2n, const float* __restrict__ W2s,
    const float* __restrict__ b2, unsigned* __restrict__ hnb8,
    float* __restrict__ hs, int M) {
  __shared__ float Wn[64 * 32];
  __shared__ float Ws[64 * 32];
  __shared__ unsigned mlds[64 * MSTRIDE];  // 9216 B
  const int tid = threadIdx.x;
  const int node0 = blockIdx.x * 64;

  for (int i = tid; i < 512; i += 256) {
    ((float4*)Wn)[i] = ((const float4*)W2n)[i];
    ((float4*)Ws)[i] = ((const float4*)W2s)[i];
  }

  // ---- gather phase: P=4 lanes per node, 16 cols each ----
  constexpr int P = 4;
  const int lrow = tid / P;            // 0..63
  const int node = node0 + lrow;       // < 100032 <= NPAD, rows2 always valid
  const int p = tid & 3;
  const uint2 be = rows2[node];
  const unsigned beg = be.x, end = be.y;  // deg-0 (incl node>=M) -> beg==end

  float acc[16];
#pragma unroll
  for (int q = 0; q < 16; ++q) acc[q] = 0.f;

  unsigned j = beg;
  for (; j + 8 <= end; j += 8) {
    int sn[8];
#pragma unroll
    for (int i = 0; i < 8; ++i) sn[i] = ssrc[j + i];
    uint4 u[8];
#pragma unroll
    for (int i = 0; i < 8; ++i) u[i] = valb4[(size_t)sn[i] * P + p];
#pragma unroll
    for (int i = 0; i < 8; ++i) {
      v2f f0 = __builtin_amdgcn_cvt_pk_f32_fp8((int)u[i].x, false);
      v2f f1 = __builtin_amdgcn_cvt_pk_f32_fp8((int)u[i].x, true);
      v2f f2 = __builtin_amdgcn_cvt_pk_f32_fp8((int)u[i].y, false);
      v2f f3 = __builtin_amdgcn_cvt_pk_f32_fp8((int)u[i].y, true);
      v2f f4 = __builtin_amdgcn_cvt_pk_f32_fp8((int)u[i].z, false);
      v2f f5 = __builtin_amdgcn_cvt_pk_f32_fp8((int)u[i].z, true);
      v2f f6 = __builtin_amdgcn_cvt_pk_f32_fp8((int)u[i].w, false);
      v2f f7 = __builtin_amdgcn_cvt_pk_f32_fp8((int)u[i].w, true);
      acc[0] += f0[0];  acc[1] += f0[1];
      acc[2] += f1[0];  acc[3] += f1[1];
      acc[4] += f2[0];  acc[5] += f2[1];
      acc[6] += f3[0];  acc[7] += f3[1];
      acc[8] += f4[0];  acc[9] += f4[1];
      acc[10] += f5[0]; acc[11] += f5[1];
      acc[12] += f6[0]; acc[13] += f6[1];
      acc[14] += f7[0]; acc[15] += f7[1];
    }
  }
  if (j < end) {
    const unsigned last = end - 1;
    int sn[8];
#pragma unroll
    for (int i = 0; i < 8; ++i) {
      unsigned jj = j + i;
      sn[i] = ssrc[jj < last ? jj : last];
    }
    uint4 u[8];
#pragma unroll
    for (int i = 0; i < 8; ++i) u[i] = valb4[(size_t)sn[i] * P + p];
#pragma unroll
    for (int i = 0; i < 8; ++i) {
      float w = ((j + i) < end) ? 1.f : 0.f;
      v2f f0 = __builtin_amdgcn_cvt_pk_f32_fp8((int)u[i].x, false);
      v2f f1 = __builtin_amdgcn_cvt_pk_f32_fp8((int)u[i].x, true);
      v2f f2 = __builtin_amdgcn_cvt_pk_f32_fp8((int)u[i].y, false);
      v2f f3 = __builtin_amdgcn_cvt_pk_f32_fp8((int)u[i].y, true);
      v2f f4 = __builtin_amdgcn_cvt_pk_f32_fp8((int)u[i].z, false);
      v2f f5 = __builtin_amdgcn_cvt_pk_f32_fp8((int)u[i].z, true);
      v2f f6 = __builtin_amdgcn_cvt_pk_f32_fp8((int)u[i].w, false);
      v2f f7 = __builtin_amdgcn_cvt_pk_f32_fp8((int)u[i].w, true);
      acc[0] = fmaf(w, f0[0], acc[0]);   acc[1] = fmaf(w, f0[1], acc[1]);
      acc[2] = fmaf(w, f1[0], acc[2]);   acc[3] = fmaf(w, f1[1], acc[3]);
      acc[4] = fmaf(w, f2[0], acc[4]);   acc[5] = fmaf(w, f2[1], acc[5]);
      acc[6] = fmaf(w, f3[0], acc[6]);   acc[7] = fmaf(w, f3[1], acc[7]);
      acc[8] = fmaf(w, f4[0], acc[8]);   acc[9] = fmaf(w, f4[1], acc[9]);
      acc[10] = fmaf(w, f5[0], acc[10]); acc[11] = fmaf(w, f5[1], acc[11]);
      acc[12] = fmaf(w, f6[0], acc[12]); acc[13] = fmaf(w, f6[1], acc[13]);
      acc[14] = fmaf(w, f7[0], acc[14]); acc[15] = fmaf(w, f7[1], acc[15]);
    }
  }

  const unsigned dg = end - beg;
  const float inv = dg ? 1.f / (float)dg : 0.f;
  uint4 pk0, pk1;
  pk0.x = pack2bf(acc[0] * inv, acc[1] * inv);
  pk0.y = pack2bf(acc[2] * inv, acc[3] * inv);
  pk0.z = pack2bf(acc[4] * inv, acc[5] * inv);
  pk0.w = pack2bf(acc[6] * inv, acc[7] * inv);
  pk1.x = pack2bf(acc[8] * inv, acc[9] * inv);
  pk1.y = pack2bf(acc[10] * inv, acc[11] * inv);
  pk1.z = pack2bf(acc[12] * inv, acc[13] * inv);
  pk1.w = pack2bf(acc[14] * inv, acc[15] * inv);
  *(uint4*)&mlds[lrow * MSTRIDE + p * 8] = pk0;
  *(uint4*)&mlds[lrow * MSTRIDE + p * 8 + 4] = pk1;
  __syncthreads();

  // ---- GEMM phase: 64 rows x dual 32 cols ----
  const int tx = tid & 7;
  const int ty = tid >> 3;  // 0..31
  const int arow = ty * 2;

  const uint2* mp[2];
  const uint2* sp[2];
#pragma unroll
  for (int r = 0; r < 2; ++r) {
    long long gr = node0 + arow + r;
    if (gr >= M) gr = M - 1;
    mp[r] = (const uint2*)&mlds[(arow + r) * MSTRIDE];
    sp[r] = (const uint2*)(xsb + gr * 64);
  }

  float4 an[2], as[2];
#pragma unroll
  for (int r = 0; r < 2; ++r) {
    an[r] = make_float4(0.f, 0.f, 0.f, 0.f);
    as[r] = make_float4(0.f, 0.f, 0.f, 0.f);
  }

#pragma unroll 2
  for (int k4 = 0; k4 < 16; ++k4) {
    float4 a[2];
#pragma unroll
    for (int r = 0; r < 2; ++r) a[r] = relu_mix(mp[r][k4], sp[r][k4]);
    float4 wn0 = *(const float4*)&Wn[(4 * k4 + 0) * 32 + 4 * tx];
    float4 wn1 = *(const float4*)&Wn[(4 * k4 + 1) * 32 + 4 * tx];
    float4 wn2 = *(const float4*)&Wn[(4 * k4 + 2) * 32 + 4 * tx];
    float4 wn3 = *(const float4*)&Wn[(4 * k4 + 3) * 32 + 4 * tx];
    float4 ws0 = *(const float4*)&Ws[(4 * k4 + 0) * 32 + 4 * tx];
    float4 ws1 = *(const float4*)&Ws[(4 * k4 + 1) * 32 + 4 * tx];
    float4 ws2 = *(const float4*)&Ws[(4 * k4 + 2) * 32 + 4 * tx];
    float4 ws3 = *(const float4*)&Ws[(4 * k4 + 3) * 32 + 4 * tx];
#pragma unroll
    for (int r = 0; r < 2; ++r) {
      fma4(a[r].x, wn0, an[r]);
      fma4(a[r].y, wn1, an[r]);
      fma4(a[r].z, wn2, an[r]);
      fma4(a[r].w, wn3, an[r]);
      fma4(a[r].x, ws0, as[r]);
      fma4(a[r].y, ws1, as[r]);
      fma4(a[r].z, ws2, as[r]);
      fma4(a[r].w, ws3, as[r]);
    }
  }

  const float4 bv = *(const float4*)&b2[4 * tx];
#pragma unroll
  for (int r = 0; r < 2; ++r) {
    int row = node0 + arow + r;
    if (row < M) {
      float4 o;
      o.x = as[r].x + bv.x;
      o.y = as[r].y + bv.y;
      o.z = as[r].z + bv.z;
      o.w = as[r].w + bv.w;
      *(float4*)&hs[(long long)row * 32 + 4 * tx] = o;
      hnb8[(size_t)row * 8 + tx] =
          packfp8x4(an[r].x, an[r].y, an[r].z, an[r].w);
    }
  }
}

// ---------------------------------------------------------------------------
// gather2: out[node][:] = mean_j fp8decode(hnb8[ssrc[j]][:]) + hs[node][:]
// Row = 32 fp8 = 32 B; table 3.2 MB -> L2-resident. P=2 lanes/node.
// ---------------------------------------------------------------------------
__global__ __launch_bounds__(256) void gather2_k(
    const uint4* __restrict__ valb4, const int* __restrict__ ssrc,
    const uint2* __restrict__ rows2, const float* __restrict__ base,
    float* __restrict__ out, int N) {
  constexpr int P = 2;
  const int node = blockIdx.x * 128 + threadIdx.x / P;
  const int p = threadIdx.x & 1;
  if (node >= N) return;
  const uint2 be = rows2[node];
  const unsigned beg = be.x, end = be.y;

  float acc[16];
#pragma unroll
  for (int q = 0; q < 16; ++q) acc[q] = 0.f;

  unsigned j = beg;
  for (; j + 8 <= end; j += 8) {
    int sn[8];
#pragma unroll
    for (int i = 0; i < 8; ++i) sn[i] = ssrc[j + i];
    uint4 u[8];
#pragma unroll
    for (int i = 0; i < 8; ++i) u[i] = valb4[(size_t)sn[i] * P + p];
#pragma unroll
    for (int i = 0; i < 8; ++i) {
      v2f f0 = __builtin_amdgcn_cvt_pk_f32_fp8((int)u[i].x, false);
      v2f f1 = __builtin_amdgcn_cvt_pk_f32_fp8((int)u[i].x, true);
      v2f f2 = __builtin_amdgcn_cvt_pk_f32_fp8((int)u[i].y, false);
      v2f f3 = __builtin_amdgcn_cvt_pk_f32_fp8((int)u[i].y, true);
      v2f f4 = __builtin_amdgcn_cvt_pk_f32_fp8((int)u[i].z, false);
      v2f f5 = __builtin_amdgcn_cvt_pk_f32_fp8((int)u[i].z, true);
      v2f f6 = __builtin_amdgcn_cvt_pk_f32_fp8((int)u[i].w, false);
      v2f f7 = __builtin_amdgcn_cvt_pk_f32_fp8((int)u[i].w, true);
      acc[0] += f0[0];  acc[1] += f0[1];
      acc[2] += f1[0];  acc[3] += f1[1];
      acc[4] += f2[0];  acc[5] += f2[1];
      acc[6] += f3[0];  acc[7] += f3[1];
      acc[8] += f4[0];  acc[9] += f4[1];
      acc[10] += f5[0]; acc[11] += f5[1];
      acc[12] += f6[0]; acc[13] += f6[1];
      acc[14] += f7[0]; acc[15] += f7[1];
    }
  }
  if (j < end) {
    const unsigned last = end - 1;
    int sn[8];
#pragma unroll
    for (int i = 0; i < 8; ++i) {
      unsigned jj = j + i;
      sn[i] = ssrc[jj < last ? jj : last];
    }
    uint4 u[8];
#pragma unroll
    for (int i = 0; i < 8; ++i) u[i] = valb4[(size_t)sn[i] * P + p];
#pragma unroll
    for (int i = 0; i < 8; ++i) {
      float w = ((j + i) < end) ? 1.f : 0.f;
      v2f f0 = __builtin_amdgcn_cvt_pk_f32_fp8((int)u[i].x, false);
      v2f f1 = __builtin_amdgcn_cvt_pk_f32_fp8((int)u[i].x, true);
      v2f f2 = __builtin_amdgcn_cvt_pk_f32_fp8((int)u[i].y, false);
      v2f f3 = __builtin_amdgcn_cvt_pk_f32_fp8((int)u[i].y, true);
      v2f f4 = __builtin_amdgcn_cvt_pk_f32_fp8((int)u[i].z, false);
      v2f f5 = __builtin_amdgcn_cvt_pk_f32_fp8((int)u[i].z, true);
      v2f f6 = __builtin_amdgcn_cvt_pk_f32_fp8((int)u[i].w, false);
      v2f f7 = __builtin_amdgcn_cvt_pk_f32_fp8((int)u[i].w, true);
      acc[0] = fmaf(w, f0[0], acc[0]);   acc[1] = fmaf(w, f0[1], acc[1]);
      acc[2] = fmaf(w, f1[0], acc[2]);   acc[3] = fmaf(w, f1[1], acc[3]);
      acc[4] = fmaf(w, f2[0], acc[4]);   acc[5] = fmaf(w, f2[1], acc[5]);
      acc[6] = fmaf(w, f3[0], acc[6]);   acc[7] = fmaf(w, f3[1], acc[7]);
      acc[8] = fmaf(w, f4[0], acc[8]);   acc[9] = fmaf(w, f4[1], acc[9]);
      acc[10] = fmaf(w, f5[0], acc[10]); acc[11] = fmaf(w, f5[1], acc[11]);
      acc[12] = fmaf(w, f6[0], acc[12]); acc[13] = fmaf(w, f6[1], acc[13]);
      acc[14] = fmaf(w, f7[0], acc[14]); acc[15] = fmaf(w, f7[1], acc[15]);
    }
  }

  const unsigned dg = end - beg;
  const float inv = dg ? 1.f / (float)dg : 0.f;
  const size_t o = (size_t)node * 32 + 16 * p;
#pragma unroll
  for (int q4 = 0; q4 < 4; ++q4) {
    float4 bv = *(const float4*)&base[o + 4 * q4];
    float4 ov;
    ov.x = acc[4 * q4 + 0] * inv + bv.x;
    ov.y = acc[4 * q4 + 1] * inv + bv.y;
    ov.z = acc[4 * q4 + 2] * inv + bv.z;
    ov.w = acc[4 * q4 + 3] * inv + bv.w;
    *(float4*)&out[o + 4 * q4] = ov;
  }
}

extern "C" void kernel_launch(void* const* d_in, const int* in_sizes, int n_in,
                              void* d_out, int out_size, void* d_ws,
                              size_t ws_size, hipStream_t stream) {
  const float* x   = (const float*)d_in[0];
  const int*   ei  = (const int*)d_in[1];  // [2, E]: row0 = src, row1 = dst
  const float* W1n = (const float*)d_in[2];
  const float* W1s = (const float*)d_in[3];
  const float* b1  = (const float*)d_in[4];
  const float* W2n = (const float*)d_in[5];
  const float* W2s = (const float*)d_in[6];
  const float* b2  = (const float*)d_in[7];
  float* out = (float*)d_out;

  const int E = in_sizes[1] / 2;  // 1,600,000
  const int M = N_NODES;
  const int* src = ei;
  const int* dst = ei + E;
  const int NSB = (E + EPB - 1) / EPB;  // 196

  // Workspace layout (bytes):
  //   ep    @ 0           12,845,056  (NB*CAP u32; layer2: hnb8 aliases, dead
  //                                    after bsort)
  //   ssrc  @ 12,845,056  12,845,056
  //   rows2 @ 25,690,112     802,816
  //   bcur  @ 26,492,928       3,136
  //   xnb8  @ 26,496,064   6,400,000  (fp8 M x 64)
  //   xsb   @ 32,896,064  12,800,000  (bf16 M x 64)
  //   hs    @ 45,696,064  12,800,000  (f32 M x 32)
  char* wsb = (char*)d_ws;
  unsigned*       ep    = (unsigned*)(wsb);
  int*            ssrc  = (int*)(wsb + 12845056);
  uint2*          rows2 = (uint2*)(wsb + 25690112);
  unsigned*       bcur  = (unsigned*)(wsb + 26492928);
  unsigned*       xnb8  = (unsigned*)(wsb + 26496064);
  unsigned short* xsb   = (unsigned short*)(wsb + 32896064);
  float*          hs    = (float*)(wsb + 45696064);
  unsigned*       hnb8  = (unsigned*)(wsb);  // aliases ep (dead after bsort)

  // 1) zero bucket cursors (3 KB)
  hipMemsetAsync(bcur, 0, NB * 4, stream);
  // 2) fusedA: 196-block edge scatter overlapped with layer-1 dual-GEMM
  fusedA_k<<<NSB + GB1, 256, 0, stream>>>(src, dst, bcur, ep, x, W1n, W1s, b1,
                                          xnb8, xsb, E, NSB, M);
  // 3) per-bucket counting sort -> ssrc runs + rows2
  bsort_k<<<NB, 256, 0, stream>>>(ep, bcur, ssrc, rows2);
  // 4) fused gather1 + gemm2: mean1 lives in LDS only
  fgg_k<<<GB1, 256, 0, stream>>>((const uint4*)xnb8, ssrc, rows2, xsb, W2n,
                                 W2s, b2, hnb8, hs, M);
  // 5) out = mean(fp8(hn)[src]) + hs
  gather2_k<<<(M + 127) / 128, 256, 0, stream>>>((const uint4*)hnb8, ssrc,
                                                 rows2, hs, out, M);
}